// Round 2
// baseline (220.176 us; speedup 1.0000x reference)
//
#include <hip/hip_runtime.h>

// MXFP (e2m1, group=32) quantize-dequantize of f32 tensor [4,32,2048,128].
// Bit-exact vs reference (verified R0: absmax 0.0).
// R1 change: no address-taken float4 element indexing — R0's `float* vp=&v.x`
// pattern defeated SROA and spilled v/o to scratch (220us vs ~85us copy
// roofline). All element math now via explicit .x/.y/.z/.w in registers.

__device__ __forceinline__ float mxfp_elem(float xd, float scale) {
    // xd = x * 2^-se (exact). Quantize to e2m1, dequant by scale.
    float ax = fabsf(xd);
    unsigned b = __float_as_uint(ax);
    int e2 = (int)(b >> 23) - 127;                               // floor(log2 ax)
    float m = __uint_as_float((b & 0x007FFFFFu) | 0x3F800000u);  // mant in [1,2)
    float q = rintf(m * 2.0f);                                   // RNE -> {2,3,4}
    float x_rnd = q * __uint_as_float((unsigned)(e2 + 126) << 23); // q * 2^(e2-1)
    float xc = fminf(fmaxf(x_rnd, 0.5f), 6.0f);                  // clamp [min,max]
    float r = copysignf(xc, xd);
    r = (ax <= 0.25f) ? 0.0f : r;                                // flush-to-zero
    return r * scale;                                            // exact pow2 mul
}

__global__ __launch_bounds__(256) void
mxfp_quant_kernel(const float* __restrict__ x, float* __restrict__ out, int n4) {
    int i = blockIdx.x * 256 + threadIdx.x;
    if (i >= n4) return;

    const float4* __restrict__ x4 = (const float4*)x;
    float4* __restrict__ o4 = (float4*)out;

    float4 v = x4[i];

    // group of 32 = 8 consecutive lanes; butterfly max over them
    float amax = fmaxf(fmaxf(fabsf(v.x), fabsf(v.y)),
                       fmaxf(fabsf(v.z), fabsf(v.w)));
    amax = fmaxf(amax, __shfl_xor(amax, 1, 64));
    amax = fmaxf(amax, __shfl_xor(amax, 2, 64));
    amax = fmaxf(amax, __shfl_xor(amax, 4, 64));

    if (amax == 0.0f) amax = 1.0f;  // reference: where(max==0, 1, max)

    int se = ((int)(__float_as_uint(amax) >> 23) - 127) - 2;  // floor(log2)-2
    se = se < -126 ? -126 : (se > 127 ? 127 : se);            // keep normal
    float scale     = __uint_as_float((unsigned)(se + 127) << 23);  // 2^se
    float inv_scale = __uint_as_float((unsigned)(127 - se) << 23);  // 2^-se

    float4 o;
    o.x = mxfp_elem(v.x * inv_scale, scale);
    o.y = mxfp_elem(v.y * inv_scale, scale);
    o.z = mxfp_elem(v.z * inv_scale, scale);
    o.w = mxfp_elem(v.w * inv_scale, scale);

    o4[i] = o;
}

extern "C" void kernel_launch(void* const* d_in, const int* in_sizes, int n_in,
                              void* d_out, int out_size, void* d_ws, size_t ws_size,
                              hipStream_t stream) {
    const float* x = (const float*)d_in[0];
    float* out = (float*)d_out;
    int n = in_sizes[0];        // 33,554,432 (divisible by 128)
    int n4 = n / 4;             // one float4 per thread; 8 threads per group
    int block = 256;
    int grid = (n4 + block - 1) / block;
    mxfp_quant_kernel<<<grid, block, 0, stream>>>(x, out, n4);
}

// Round 3
// 218.802 us; speedup vs baseline: 1.0063x; 1.0063x over previous
//
#include <hip/hip_runtime.h>

// MXFP (e2m1, group=32) quantize-dequantize of f32 tensor [4,32,2048,128].
// Bit-exact vs reference (R0/R1: absmax 0.0).
// R2: rocprof table (sorted desc by dur_us) shows only 79-81us harness poison
// fills -> our kernel dispatch is <79us; bench dur_us=220 includes ~140us of
// harness reset traffic. This round maximizes streaming efficiency anyway:
//   - 4 float4 tiles per thread (block-tiled, stride 256) -> 4 outstanding
//     dwordx4 loads per thread for latency hiding
//   - nontemporal load/store (zero-reuse streams; skip L2 allocate)

typedef float f32x4 __attribute__((ext_vector_type(4)));

__device__ __forceinline__ float mxfp_elem(float xd, float scale) {
    // xd = x * 2^-se (exact). Quantize to e2m1 (RNE), dequant by scale.
    float ax = fabsf(xd);
    unsigned b = __float_as_uint(ax);
    int e2 = (int)(b >> 23) - 127;                               // floor(log2 ax)
    float m = __uint_as_float((b & 0x007FFFFFu) | 0x3F800000u);  // mant in [1,2)
    float q = rintf(m * 2.0f);                                   // RNE -> {2,3,4}
    float x_rnd = q * __uint_as_float((unsigned)(e2 + 126) << 23); // q*2^(e2-1)
    float xc = fminf(fmaxf(x_rnd, 0.5f), 6.0f);                  // clamp
    float r = copysignf(xc, xd);
    r = (ax <= 0.25f) ? 0.0f : r;                                // flush-to-zero
    return r * scale;                                            // exact pow2 mul
}

__device__ __forceinline__ f32x4 mxfp_tile(f32x4 v) {
    // group of 32 = 8 consecutive lanes; butterfly max over them
    float amax = fmaxf(fmaxf(fabsf(v.x), fabsf(v.y)),
                       fmaxf(fabsf(v.z), fabsf(v.w)));
    amax = fmaxf(amax, __shfl_xor(amax, 1, 64));
    amax = fmaxf(amax, __shfl_xor(amax, 2, 64));
    amax = fmaxf(amax, __shfl_xor(amax, 4, 64));
    if (amax == 0.0f) amax = 1.0f;          // reference: where(max==0, 1, max)

    int se = ((int)(__float_as_uint(amax) >> 23) - 127) - 2;  // floor(log2)-2
    se = se < -126 ? -126 : (se > 127 ? 127 : se);            // keep normal
    float scale     = __uint_as_float((unsigned)(se + 127) << 23);  // 2^se
    float inv_scale = __uint_as_float((unsigned)(127 - se) << 23);  // 2^-se

    f32x4 o;
    o.x = mxfp_elem(v.x * inv_scale, scale);
    o.y = mxfp_elem(v.y * inv_scale, scale);
    o.z = mxfp_elem(v.z * inv_scale, scale);
    o.w = mxfp_elem(v.w * inv_scale, scale);
    return o;
}

__global__ __launch_bounds__(256) void
mxfp_quant_kernel(const float* __restrict__ x, float* __restrict__ out, int n4) {
    const f32x4* __restrict__ x4 = (const f32x4*)x;
    f32x4* __restrict__ o4 = (f32x4*)out;

    // Each block owns a contiguous tile of 1024 float4s; each thread handles
    // 4 float4s at stride 256 (keeps 8-lane group alignment + coalescing).
    int base = blockIdx.x * 1024 + (int)threadIdx.x;

    if (base + 768 < n4) {
        f32x4 v0 = __builtin_nontemporal_load(&x4[base]);
        f32x4 v1 = __builtin_nontemporal_load(&x4[base + 256]);
        f32x4 v2 = __builtin_nontemporal_load(&x4[base + 512]);
        f32x4 v3 = __builtin_nontemporal_load(&x4[base + 768]);
        f32x4 o0 = mxfp_tile(v0);
        f32x4 o1 = mxfp_tile(v1);
        f32x4 o2 = mxfp_tile(v2);
        f32x4 o3 = mxfp_tile(v3);
        __builtin_nontemporal_store(o0, &o4[base]);
        __builtin_nontemporal_store(o1, &o4[base + 256]);
        __builtin_nontemporal_store(o2, &o4[base + 512]);
        __builtin_nontemporal_store(o3, &o4[base + 768]);
    } else {
        // generic tail (unused for the bench shape: n4 = 8192*1024 exactly)
        for (int k = 0; k < 4; ++k) {
            int idx = base + 256 * k;
            if (idx < n4) {
                f32x4 o = mxfp_tile(x4[idx]);
                __builtin_nontemporal_store(o, &o4[idx]);
            }
        }
    }
}

extern "C" void kernel_launch(void* const* d_in, const int* in_sizes, int n_in,
                              void* d_out, int out_size, void* d_ws, size_t ws_size,
                              hipStream_t stream) {
    const float* x = (const float*)d_in[0];
    float* out = (float*)d_out;
    int n = in_sizes[0];        // 33,554,432
    int n4 = n / 4;             // 8,388,608 float4s
    int block = 256;
    int grid = (n4 + 1023) / 1024;   // 4 float4s per thread
    mxfp_quant_kernel<<<grid, block, 0, stream>>>(x, out, n4);
}